// Round 1
// baseline (3694.852 us; speedup 1.0000x reference)
//
#include <hip/hip_runtime.h>

#define T_ 12
#define B_ 256
#define N_ 35
#define M_ 29
#define H_ 64
#define R_ 7
#define NB_ 3
#define HEADS_ 8
#define DH_ 8
#define THREADS 512

// Wrel[r,m,h] = sum_b coef[r,b] * V[b,m,h]   (time-invariant, into d_ws)
__global__ void wrel_kernel(const float* __restrict__ coef, const float* __restrict__ V,
                            float* __restrict__ Wrel) {
    int idx = blockIdx.x * 256 + threadIdx.x;
    if (idx >= R_ * M_ * H_) return;
    int r = idx / (M_ * H_);
    int mh = idx - r * (M_ * H_);
    float acc = 0.f;
#pragma unroll
    for (int bb = 0; bb < NB_; ++bb) acc += coef[r * NB_ + bb] * V[bb * (M_ * H_) + mh];
    Wrel[idx] = acc;
}

// One block per batch element b; loops over all T steps (per-b independence).
__launch_bounds__(THREADS, 1)
__global__ void staa_kernel(
    const float* __restrict__ x, const float* __restrict__ As,
    const float* __restrict__ Af, const float* __restrict__ At,
    const float* __restrict__ h0, const float* __restrict__ Wq,
    const float* __restrict__ Wk, const float* __restrict__ Wrel,
    const float* __restrict__ Uz, const float* __restrict__ Wz, const float* __restrict__ bz,
    const float* __restrict__ Ur, const float* __restrict__ Wrg, const float* __restrict__ brg,
    const float* __restrict__ Uh, const float* __restrict__ Wh, const float* __restrict__ bh,
    float* __restrict__ out)
{
    const int b = blockIdx.x;
    const int tid = threadIdx.x;

    // LDS budget: 4200+8960+9216+8960+8960+5040+5040+15120 = 65496 B (<= 64 KiB)
    __shared__ float xs[N_][M_ + 1];       // x_t  [35][30]
    __shared__ float qbuf[N_ * H_];        // q -> xw_r -> r*h
    __shared__ float kT[H_ * (N_ + 1)];    // k^T [64][36] -> msg [35][64] (2240<=2304)
    __shared__ float hbuf[N_ * H_];        // h_prev slice for stream r
    __shared__ float zbuf[N_ * H_];        // z gate
    __shared__ float sc[N_][36];           // per-head scores -> A_r
    __shared__ float Ssh[N_][36];          // accumulated softmax (mean/8 omitted: cancels in l2norm)
    __shared__ float An[3][N_][36];        // normalized adjacencies

    const float inv_sqrt_dh = 0.3535533905932738f;  // 1/sqrt(8)

    for (int t = 0; t < T_; ++t) {
        const float* __restrict__ hprev =
            (t == 0) ? h0 : (out + (size_t)(t - 1) * (R_ * B_ * N_ * H_));
        const float* __restrict__ xt = x + ((size_t)t * B_ + b) * (N_ * M_);

        // ---- stage 1: load x_t, zero S accumulator ----
        for (int idx = tid; idx < N_ * M_; idx += THREADS)
            xs[idx / M_][idx % M_] = xt[idx];
        for (int idx = tid; idx < N_ * 36; idx += THREADS)
            Ssh[idx / 36][idx % 36] = 0.f;
        __syncthreads();

        // ---- stage 2: q = x@Wq, kT = (x@Wk)^T ----
        for (int idx = tid; idx < 2 * N_ * H_; idx += THREADS) {
            int which = idx / (N_ * H_);
            int rem = idx - which * (N_ * H_);
            int n = rem / H_, hc = rem % H_;
            const float* W = which ? Wk : Wq;
            float acc = 0.f;
#pragma unroll
            for (int m = 0; m < M_; ++m) acc += xs[n][m] * W[m * H_ + hc];
            if (which) kT[hc * (N_ + 1) + n] = acc;   // transposed (avoids 32-way conflict in QK^T)
            else       qbuf[n * H_ + hc] = acc;
        }
        __syncthreads();

        // ---- stage 3: S = sum_heads softmax(q k^T * scale) ----
        for (int hd = 0; hd < HEADS_; ++hd) {
            for (int idx = tid; idx < N_ * N_; idx += THREADS) {
                int n = idx / N_, m2 = idx - n * N_;
                float acc = 0.f;
#pragma unroll
                for (int d = 0; d < DH_; ++d)
                    acc += qbuf[n * H_ + hd * DH_ + d] * kT[(hd * DH_ + d) * (N_ + 1) + m2];
                sc[n][m2] = acc * inv_sqrt_dh;
            }
            __syncthreads();
            if (tid < N_) {  // serial per-row softmax (35 rows); cheap at this size
                int n = tid;
                float mx = sc[n][0];
                for (int m2 = 1; m2 < N_; ++m2) mx = fmaxf(mx, sc[n][m2]);
                float ssum = 0.f;
                for (int m2 = 0; m2 < N_; ++m2) ssum += __expf(sc[n][m2] - mx);
                float inv = 1.f / ssum;
                for (int m2 = 0; m2 < N_; ++m2)
                    Ssh[n][m2] += __expf(sc[n][m2] - mx) * inv;
            }
            __syncthreads();
        }

        // ---- stage 4: An_{s,f,t} = l2norm(A * S) along n (per column j) ----
        if (tid < 3 * N_) {
            int mat = tid / N_, j = tid - mat * N_;
            const float* A = (mat == 0) ? As : ((mat == 1) ? Af : At);
            float ss = 0.f;
            for (int n = 0; n < N_; ++n) {
                float v = A[n * N_ + j] * Ssh[n][j];
                ss += v * v;
            }
            float inv = 1.f / fmaxf(sqrtf(ss), 1e-12f);
            for (int n = 0; n < N_; ++n)
                An[mat][n][j] = A[n * N_ + j] * Ssh[n][j] * inv;
        }
        __syncthreads();

        // ---- stage 5: relation loop ----
        for (int r = 0; r < R_; ++r) {
            float c0, c1, c2;  // A_r = c0*An_s + c1*An_f + c2*An_t  (uniform per r)
            switch (r) {
                case 0: c0 = 1.f; c1 = 0.f; c2 = 0.f; break;
                case 1: c0 = 0.f; c1 = 1.f; c2 = 0.f; break;
                case 2: c0 = 0.f; c1 = 0.f; c2 = 1.f; break;
                case 3: c0 = .5f; c1 = .5f; c2 = 0.f; break;
                case 4: c0 = .5f; c1 = 0.f; c2 = .5f; break;
                case 5: c0 = 0.f; c1 = .5f; c2 = .5f; break;
                default: c0 = c1 = c2 = (1.f / 3.f); break;
            }
            const float* __restrict__ Wr = Wrel + r * (M_ * H_);
            const float* __restrict__ hpr = hprev + (size_t)(r * B_ + b) * (N_ * H_);

            // 5a: xw = x@Wrel_r -> qbuf ; stage h_prev -> hbuf ; A_r -> sc
            for (int idx = tid; idx < 2 * N_ * H_ + N_ * N_; idx += THREADS) {
                if (idx < N_ * H_) {
                    int k = idx / H_, hc = idx - k * H_;
                    float acc = 0.f;
#pragma unroll
                    for (int m = 0; m < M_; ++m) acc += xs[k][m] * Wr[m * H_ + hc];
                    qbuf[idx] = acc;
                } else if (idx < 2 * N_ * H_) {
                    int rem = idx - N_ * H_;
                    hbuf[rem] = hpr[rem];
                } else {
                    int rem = idx - 2 * N_ * H_;
                    int n = rem / N_, k = rem - n * N_;
                    sc[n][k] = c0 * An[0][n][k] + c1 * An[1][n][k] + c2 * An[2][n][k];
                }
            }
            __syncthreads();

            // 5b: msg = relu(A_r @ xw) -> kT buffer (as [35][64])
            float* msg = kT;
            for (int idx = tid; idx < N_ * H_; idx += THREADS) {
                int n = idx / H_, hc = idx - n * H_;
                float acc = 0.f;
#pragma unroll
                for (int k = 0; k < N_; ++k) acc += sc[n][k] * qbuf[k * H_ + hc];
                msg[idx] = fmaxf(acc, 0.f);
            }
            __syncthreads();

            // 5c: z = sig(msg@Uz + h@Wz + bz), rg = sig(msg@Ur + h@Wrg + brg); rh -> qbuf
            for (int idx = tid; idx < N_ * H_; idx += THREADS) {
                int n = idx / H_, hc = idx - n * H_;
                float az = bz[hc], ar = brg[hc];
#pragma unroll 8
                for (int j = 0; j < H_; ++j) {
                    float mj = msg[n * H_ + j];
                    float hj = hbuf[n * H_ + j];
                    az += mj * Uz[j * H_ + hc] + hj * Wz[j * H_ + hc];
                    ar += mj * Ur[j * H_ + hc] + hj * Wrg[j * H_ + hc];
                }
                float zv = 1.f / (1.f + __expf(-az));
                float rv = 1.f / (1.f + __expf(-ar));
                zbuf[idx] = zv;
                qbuf[idx] = rv * hbuf[idx];   // r (.) h   (qbuf free after 5b)
            }
            __syncthreads();

            // 5d: hh = tanh(msg@Uh + rh@Wh + bh); h_new = h + z*(hh-h) -> out[t,r,b]
            float* __restrict__ outt = out + (((size_t)t * R_ + r) * B_ + b) * (N_ * H_);
            for (int idx = tid; idx < N_ * H_; idx += THREADS) {
                int n = idx / H_, hc = idx - n * H_;
                float ah = bh[hc];
#pragma unroll 8
                for (int j = 0; j < H_; ++j) {
                    ah += msg[n * H_ + j] * Uh[j * H_ + hc] + qbuf[n * H_ + j] * Wh[j * H_ + hc];
                }
                float e = __expf(2.f * ah);          // tanh, overflow-safe
                float hh = 1.f - 2.f / (1.f + e);
                float hp = hbuf[idx];
                float zv = zbuf[idx];
                outt[idx] = hp + zv * (hh - hp);
            }
            __syncthreads();
        }
    }
}

extern "C" void kernel_launch(void* const* d_in, const int* in_sizes, int n_in,
                              void* d_out, int out_size, void* d_ws, size_t ws_size,
                              hipStream_t stream) {
    const float* x    = (const float*)d_in[0];
    const float* As   = (const float*)d_in[1];
    const float* Af   = (const float*)d_in[2];
    const float* At   = (const float*)d_in[3];
    const float* h0   = (const float*)d_in[4];
    const float* Wq   = (const float*)d_in[5];
    const float* Wk   = (const float*)d_in[6];
    const float* V    = (const float*)d_in[7];
    const float* coef = (const float*)d_in[8];
    const float* Uz   = (const float*)d_in[9];
    const float* Wz   = (const float*)d_in[10];
    const float* bz   = (const float*)d_in[11];
    const float* Ur   = (const float*)d_in[12];
    const float* Wrg  = (const float*)d_in[13];
    const float* brg  = (const float*)d_in[14];
    const float* Uh   = (const float*)d_in[15];
    const float* Wh   = (const float*)d_in[16];
    const float* bh   = (const float*)d_in[17];
    float* out  = (float*)d_out;
    float* Wrel = (float*)d_ws;  // 7*29*64 floats = 51968 B

    hipLaunchKernelGGL(wrel_kernel, dim3((R_ * M_ * H_ + 255) / 256), dim3(256), 0, stream,
                       coef, V, Wrel);
    hipLaunchKernelGGL(staa_kernel, dim3(B_), dim3(THREADS), 0, stream,
                       x, As, Af, At, h0, Wq, Wk, Wrel,
                       Uz, Wz, bz, Ur, Wrg, brg, Uh, Wh, bh, out);
}

// Round 2
// 1683.269 us; speedup vs baseline: 2.1950x; 2.1950x over previous
//
#include <hip/hip_runtime.h>

#define T_ 12
#define B_ 256
#define N_ 35
#define M_ 29
#define H_ 64
#define R_ 7
#define NB_ 3
#define HEADS_ 8
#define THREADS 512

// LDS layout (floats). Total 40208 floats = 160832 B (<= 160 KiB).
#define OFF_WP   0        // [64][64][4] packed {Uz,Wz,Ur,Wrg}[j][hc]  (16384)
#define OFF_UH   16384    // Uh [64][64]                                (4096)
#define OFF_WH   20480    // Wh [64][64]                                (4096)
#define OFF_BIAS 24576    // [3][64] bz,brg,bh                          (192)
#define OFF_XS   24768    // x_t [40][32]                               (1280)
#define OFF_X1   26048    // q / xw / rh  [40][64]                      (2560)
#define OFF_X2   28608    // kT [64][37] / msg [40][64]                 (2560)
#define OFF_HB   31168    // h_prev [40][64]                            (2560)
#define OFF_SC   33728    // scores / A_r [40][36]                      (1440)
#define OFF_SSH  35168    // softmax-sum [35][36]                       (1260)
#define OFF_AN   36428    // An [3][35][36]                             (3780)
#define LDS_FLOATS 40208

__global__ void wrel_kernel(const float* __restrict__ coef, const float* __restrict__ V,
                            float* __restrict__ Wrel) {
    int idx = blockIdx.x * 256 + threadIdx.x;
    if (idx >= R_ * M_ * H_) return;
    int r = idx / (M_ * H_);
    int mh = idx - r * (M_ * H_);
    float acc = 0.f;
#pragma unroll
    for (int bb = 0; bb < NB_; ++bb) acc += coef[r * NB_ + bb] * V[bb * (M_ * H_) + mh];
    Wrel[idx] = acc;
}

__launch_bounds__(THREADS, 2)
__global__ void staa_kernel(
    const float* __restrict__ x, const float* __restrict__ As,
    const float* __restrict__ Af, const float* __restrict__ At,
    const float* __restrict__ h0, const float* __restrict__ Wq,
    const float* __restrict__ Wk, const float* __restrict__ Wrel,
    const float* __restrict__ Uz, const float* __restrict__ Wz, const float* __restrict__ bz,
    const float* __restrict__ Ur, const float* __restrict__ Wrg, const float* __restrict__ brg,
    const float* __restrict__ Uh, const float* __restrict__ Wh, const float* __restrict__ bh,
    float* __restrict__ out)
{
    extern __shared__ float ls[];
    const int b  = blockIdx.x;
    const int tid = threadIdx.x;
    const int wv = tid >> 6;   // wave 0..7
    const int ln = tid & 63;   // lane = hidden channel

    float* WP  = ls + OFF_WP;
    float* UHs = ls + OFF_UH;
    float* WHs = ls + OFF_WH;
    float* BIA = ls + OFF_BIAS;
    float* xs  = ls + OFF_XS;
    float* X1  = ls + OFF_X1;
    float* X2  = ls + OFF_X2;
    float* hb  = ls + OFF_HB;
    float* sc  = ls + OFF_SC;
    float* Ssh = ls + OFF_SSH;
    float* An  = ls + OFF_AN;

    // ---- init: stage GRU weights into LDS; zero pad rows ----
    for (int idx = tid; idx < H_ * H_; idx += THREADS) {
        float4 w4;
        w4.x = Uz[idx]; w4.y = Wz[idx]; w4.z = Ur[idx]; w4.w = Wrg[idx];
        *reinterpret_cast<float4*>(&WP[idx * 4]) = w4;
        UHs[idx] = Uh[idx];
        WHs[idx] = Wh[idx];
    }
    if (tid < H_) { BIA[tid] = bz[tid]; BIA[H_ + tid] = brg[tid]; BIA[2 * H_ + tid] = bh[tid]; }
    for (int idx = tid; idx < 5 * H_; idx += THREADS) {   // rows 35..39
        X1[N_ * H_ + idx] = 0.f; X2[N_ * H_ + idx] = 0.f; hb[N_ * H_ + idx] = 0.f;
    }
    for (int idx = tid; idx < 5 * 36; idx += THREADS) sc[N_ * 36 + idx] = 0.f;
    if (tid < 3 * N_) { int mat = tid / N_, n = tid - N_ * mat; An[mat * 1260 + n * 36 + 35] = 0.f; }
    __syncthreads();

    for (int t = 0; t < T_; ++t) {
        const float* __restrict__ hprev =
            (t == 0) ? h0 : (out + (size_t)(t - 1) * (R_ * B_ * N_ * H_));
        const float* __restrict__ xt = x + ((size_t)t * B_ + b) * (N_ * M_);

        // ---- stage 1: load x_t, zero Ssh ----
        for (int idx = tid; idx < N_ * M_; idx += THREADS)
            xs[(idx / M_) * 32 + (idx % M_)] = xt[idx];
        for (int idx = tid; idx < N_ * 36; idx += THREADS) Ssh[idx] = 0.f;
        __syncthreads();

        // ---- stage 2: q = x@Wq (X1 rows), kT = (x@Wk)^T (X2, stride 37) ----
        {
            const int mat = wv & 1;
            const int r0 = wv >> 1;                 // rows r0 + 4i, i<9
            const float* __restrict__ W = mat ? Wk : Wq;
            float acc[9];
#pragma unroll
            for (int i = 0; i < 9; ++i) acc[i] = 0.f;
            for (int mb = 0; mb < 28; mb += 4) {
                float w0 = W[(mb + 0) * H_ + ln], w1 = W[(mb + 1) * H_ + ln];
                float w2 = W[(mb + 2) * H_ + ln], w3 = W[(mb + 3) * H_ + ln];
#pragma unroll
                for (int i = 0; i < 9; ++i) {
                    const float4 xv = *reinterpret_cast<const float4*>(&xs[(r0 + 4 * i) * 32 + mb]);
                    acc[i] += xv.x * w0 + xv.y * w1 + xv.z * w2 + xv.w * w3;
                }
            }
            {
                float w0 = W[28 * H_ + ln];
#pragma unroll
                for (int i = 0; i < 9; ++i) acc[i] += xs[(r0 + 4 * i) * 32 + 28] * w0;
            }
#pragma unroll
            for (int i = 0; i < 9; ++i) {
                int n = r0 + 4 * i;
                if (n < N_) {
                    if (mat) X2[ln * 37 + n] = acc[i];
                    else     X1[n * H_ + ln] = acc[i];
                }
            }
        }
        __syncthreads();

        // ---- stage 3: S = sum_heads softmax(q kT / sqrt(8)) ----
        for (int hd = 0; hd < HEADS_; ++hd) {
            for (int idx = tid; idx < N_ * 36; idx += THREADS) {
                int n = idx / 36, m2 = idx - 36 * n;
                if (m2 < N_) {
                    const float4 q0 = *reinterpret_cast<const float4*>(&X1[n * H_ + hd * 8]);
                    const float4 q1 = *reinterpret_cast<const float4*>(&X1[n * H_ + hd * 8 + 4]);
                    float s = q0.x * X2[(hd * 8 + 0) * 37 + m2] + q0.y * X2[(hd * 8 + 1) * 37 + m2]
                            + q0.z * X2[(hd * 8 + 2) * 37 + m2] + q0.w * X2[(hd * 8 + 3) * 37 + m2]
                            + q1.x * X2[(hd * 8 + 4) * 37 + m2] + q1.y * X2[(hd * 8 + 5) * 37 + m2]
                            + q1.z * X2[(hd * 8 + 6) * 37 + m2] + q1.w * X2[(hd * 8 + 7) * 37 + m2];
                    sc[idx] = s * 0.3535533905932738f;
                }
            }
            __syncthreads();
            if (tid < 280) {  // 8 lanes per row
                int n = tid >> 3, sub = tid & 7;
                float v[5]; float mx = -1e30f;
#pragma unroll
                for (int i = 0; i < 5; ++i) {
                    int c = sub + 8 * i;
                    v[i] = (c < N_) ? sc[n * 36 + c] : -1e30f;
                    mx = fmaxf(mx, v[i]);
                }
                mx = fmaxf(mx, __shfl_xor(mx, 1));
                mx = fmaxf(mx, __shfl_xor(mx, 2));
                mx = fmaxf(mx, __shfl_xor(mx, 4));
                float sum = 0.f;
#pragma unroll
                for (int i = 0; i < 5; ++i) { v[i] = __expf(v[i] - mx); sum += v[i]; }
                sum += __shfl_xor(sum, 1);
                sum += __shfl_xor(sum, 2);
                sum += __shfl_xor(sum, 4);
                float inv = 1.f / sum;
#pragma unroll
                for (int i = 0; i < 5; ++i) {
                    int c = sub + 8 * i;
                    if (c < N_) Ssh[n * 36 + c] += v[i] * inv;
                }
            }
            __syncthreads();
        }

        // ---- stage 4: An = l2norm(A * S) along n, 4 lanes per (mat,col) ----
        if (tid < 420) {
            int g = tid >> 2, sub = tid & 3;
            int mat = g / N_, j = g - N_ * mat;
            const float* __restrict__ A = (mat == 0) ? As : ((mat == 1) ? Af : At);
            float vals[9]; float ss = 0.f;
#pragma unroll
            for (int i = 0; i < 9; ++i) {
                int n = sub + 4 * i;
                float vv = 0.f;
                if (n < N_) vv = A[n * N_ + j] * Ssh[n * 36 + j];
                vals[i] = vv; ss += vv * vv;
            }
            ss += __shfl_xor(ss, 1);
            ss += __shfl_xor(ss, 2);
            float inv = 1.f / fmaxf(sqrtf(ss), 1e-12f);
#pragma unroll
            for (int i = 0; i < 9; ++i) {
                int n = sub + 4 * i;
                if (n < N_) An[mat * 1260 + n * 36 + j] = vals[i] * inv;
            }
        }
        __syncthreads();

        // ---- stage 5: relation streams ----
        for (int r = 0; r < R_; ++r) {
            float c0, c1, c2;
            switch (r) {
                case 0: c0 = 1.f; c1 = 0.f; c2 = 0.f; break;
                case 1: c0 = 0.f; c1 = 1.f; c2 = 0.f; break;
                case 2: c0 = 0.f; c1 = 0.f; c2 = 1.f; break;
                case 3: c0 = .5f; c1 = .5f; c2 = 0.f; break;
                case 4: c0 = .5f; c1 = 0.f; c2 = .5f; break;
                case 5: c0 = 0.f; c1 = .5f; c2 = .5f; break;
                default: c0 = c1 = c2 = (1.f / 3.f); break;
            }
            const float* __restrict__ Wr  = Wrel + r * (M_ * H_);
            const float* __restrict__ hpr = hprev + (size_t)(r * B_ + b) * (N_ * H_);

            // 5a: xw = x@Wr -> X1 rows; stage h -> hb; A_r -> sc; zero X1 row 35
            {
                float acc[5];
#pragma unroll
                for (int i = 0; i < 5; ++i) acc[i] = 0.f;
                for (int mb = 0; mb < 28; mb += 4) {
                    float w0 = Wr[(mb + 0) * H_ + ln], w1 = Wr[(mb + 1) * H_ + ln];
                    float w2 = Wr[(mb + 2) * H_ + ln], w3 = Wr[(mb + 3) * H_ + ln];
#pragma unroll
                    for (int i = 0; i < 5; ++i) {
                        const float4 xv = *reinterpret_cast<const float4*>(&xs[(wv + 8 * i) * 32 + mb]);
                        acc[i] += xv.x * w0 + xv.y * w1 + xv.z * w2 + xv.w * w3;
                    }
                }
                {
                    float w0 = Wr[28 * H_ + ln];
#pragma unroll
                    for (int i = 0; i < 5; ++i) acc[i] += xs[(wv + 8 * i) * 32 + 28] * w0;
                }
#pragma unroll
                for (int i = 0; i < 5; ++i) {
                    int n = wv + 8 * i;
                    if (n < N_) X1[n * H_ + ln] = acc[i];
                }
            }
            for (int idx = tid; idx < (N_ * H_) / 4; idx += THREADS)
                *reinterpret_cast<float4*>(&hb[idx * 4]) =
                    *reinterpret_cast<const float4*>(&hpr[idx * 4]);
            for (int idx = tid; idx < N_ * 36; idx += THREADS)
                sc[idx] = c0 * An[idx] + c1 * An[1260 + idx] + c2 * An[2520 + idx];
            if (tid < H_) X1[N_ * H_ + tid] = 0.f;   // pad row 35 of xw
            __syncthreads();

            // 5b: msg = relu(A_r @ xw) -> X2 rows
            {
                float acc[5];
#pragma unroll
                for (int i = 0; i < 5; ++i) acc[i] = 0.f;
                for (int kb = 0; kb < 36; kb += 4) {
                    float x0 = X1[(kb + 0) * H_ + ln], x1 = X1[(kb + 1) * H_ + ln];
                    float x2 = X1[(kb + 2) * H_ + ln], x3 = X1[(kb + 3) * H_ + ln];
#pragma unroll
                    for (int i = 0; i < 5; ++i) {
                        const float4 av = *reinterpret_cast<const float4*>(&sc[(wv + 8 * i) * 36 + kb]);
                        acc[i] += av.x * x0 + av.y * x1 + av.z * x2 + av.w * x3;
                    }
                }
#pragma unroll
                for (int i = 0; i < 5; ++i) X2[(wv + 8 * i) * H_ + ln] = fmaxf(acc[i], 0.f);
            }
            __syncthreads();

            // phase A: az/ar/am over j; z,r in regs; rh -> X1
            float am[5], zz[5], hv0[5];
            {
                float az[5], ar[5];
#pragma unroll
                for (int i = 0; i < 5; ++i) { az[i] = 0.f; ar[i] = 0.f; am[i] = 0.f; }
#pragma unroll 2
                for (int jb = 0; jb < H_; jb += 4) {
                    const float4 p0 = *reinterpret_cast<const float4*>(&WP[((jb + 0) * H_ + ln) * 4]);
                    const float4 p1 = *reinterpret_cast<const float4*>(&WP[((jb + 1) * H_ + ln) * 4]);
                    const float4 p2 = *reinterpret_cast<const float4*>(&WP[((jb + 2) * H_ + ln) * 4]);
                    const float4 p3 = *reinterpret_cast<const float4*>(&WP[((jb + 3) * H_ + ln) * 4]);
                    float u0 = UHs[(jb + 0) * H_ + ln], u1 = UHs[(jb + 1) * H_ + ln];
                    float u2 = UHs[(jb + 2) * H_ + ln], u3 = UHs[(jb + 3) * H_ + ln];
#pragma unroll
                    for (int i = 0; i < 5; ++i) {
                        const int row = (wv + 8 * i) * H_;
                        const float4 mv = *reinterpret_cast<const float4*>(&X2[row + jb]);
                        const float4 hh = *reinterpret_cast<const float4*>(&hb[row + jb]);
                        az[i] += mv.x * p0.x + hh.x * p0.y + mv.y * p1.x + hh.y * p1.y
                               + mv.z * p2.x + hh.z * p2.y + mv.w * p3.x + hh.w * p3.y;
                        ar[i] += mv.x * p0.z + hh.x * p0.w + mv.y * p1.z + hh.y * p1.w
                               + mv.z * p2.z + hh.z * p2.w + mv.w * p3.z + hh.w * p3.w;
                        am[i] += mv.x * u0 + mv.y * u1 + mv.z * u2 + mv.w * u3;
                    }
                }
#pragma unroll
                for (int i = 0; i < 5; ++i) {
                    const int row = (wv + 8 * i) * H_ + ln;
                    float hv = hb[row];
                    float zv = 1.f / (1.f + __expf(-(az[i] + BIA[ln])));
                    float rv = 1.f / (1.f + __expf(-(ar[i] + BIA[H_ + ln])));
                    zz[i] = zv; hv0[i] = hv;
                    X1[row] = rv * hv;
                }
            }
            __syncthreads();

            // phase B: am += rh@Wh; hh = tanh; h_new -> out
            {
#pragma unroll 2
                for (int jb = 0; jb < H_; jb += 4) {
                    float w0 = WHs[(jb + 0) * H_ + ln], w1 = WHs[(jb + 1) * H_ + ln];
                    float w2 = WHs[(jb + 2) * H_ + ln], w3 = WHs[(jb + 3) * H_ + ln];
#pragma unroll
                    for (int i = 0; i < 5; ++i) {
                        const float4 rv = *reinterpret_cast<const float4*>(&X1[(wv + 8 * i) * H_ + jb]);
                        am[i] += rv.x * w0 + rv.y * w1 + rv.z * w2 + rv.w * w3;
                    }
                }
                float* __restrict__ outt = out + (((size_t)t * R_ + r) * B_ + b) * (N_ * H_);
#pragma unroll
                for (int i = 0; i < 5; ++i) {
                    int n = wv + 8 * i;
                    if (n < N_) {
                        float e = __expf(2.f * (am[i] + BIA[2 * H_ + ln]));
                        float hhv = 1.f - 2.f / (1.f + e);
                        float hp = hv0[i];
                        outt[n * H_ + ln] = hp + zz[i] * (hhv - hp);
                    }
                }
            }
            __syncthreads();
        }
    }
}

extern "C" void kernel_launch(void* const* d_in, const int* in_sizes, int n_in,
                              void* d_out, int out_size, void* d_ws, size_t ws_size,
                              hipStream_t stream) {
    const float* x    = (const float*)d_in[0];
    const float* As   = (const float*)d_in[1];
    const float* Af   = (const float*)d_in[2];
    const float* At   = (const float*)d_in[3];
    const float* h0   = (const float*)d_in[4];
    const float* Wq   = (const float*)d_in[5];
    const float* Wk   = (const float*)d_in[6];
    const float* V    = (const float*)d_in[7];
    const float* coef = (const float*)d_in[8];
    const float* Uz   = (const float*)d_in[9];
    const float* Wz   = (const float*)d_in[10];
    const float* bz   = (const float*)d_in[11];
    const float* Ur   = (const float*)d_in[12];
    const float* Wrg  = (const float*)d_in[13];
    const float* brg  = (const float*)d_in[14];
    const float* Uh   = (const float*)d_in[15];
    const float* Wh   = (const float*)d_in[16];
    const float* bh   = (const float*)d_in[17];
    float* out  = (float*)d_out;
    float* Wrel = (float*)d_ws;

    const int lds_bytes = LDS_FLOATS * 4;  // 160832 B
    hipFuncSetAttribute((const void*)staa_kernel,
                        hipFuncAttributeMaxDynamicSharedMemorySize, lds_bytes);

    hipLaunchKernelGGL(wrel_kernel, dim3((R_ * M_ * H_ + 255) / 256), dim3(256), 0, stream,
                       coef, V, Wrel);
    hipLaunchKernelGGL(staa_kernel, dim3(B_), dim3(THREADS), lds_bytes, stream,
                       x, As, Af, At, h0, Wq, Wk, Wrel,
                       Uz, Wz, bz, Ur, Wrg, brg, Uh, Wh, bh, out);
}

// Round 3
// 679.634 us; speedup vs baseline: 5.4365x; 2.4767x over previous
//
#include <hip/hip_runtime.h>

typedef short short8 __attribute__((ext_vector_type(8)));
typedef short short4v __attribute__((ext_vector_type(4)));
typedef float f32x4 __attribute__((ext_vector_type(4)));

#define T_ 12
#define B_ 256
#define N_ 35
#define M_ 29
#define H_ 64
#define R_ 7
#define THREADS 512

// ---------------- LDS byte layout (total exactly 160 KiB) ----------------
// statics:
#define W6_OFF    0        // 6 mats x [4nt][2ks][64 lanes][16B] = 49152
#define WQK_OFF   49152    // 2 mats x [4nt][64][16B]            = 8192
#define WRELF_OFF 57344    // 7 r    x [4nt][64][16B]            = 28672
#define XFRAG_OFF 86016    // 3 mt   x [64][16B]                 = 3072
#define BIAS_OFF  89088    // bz@0 brg@256 bh@512 (fp32)         = 768
#define POOL      90112    // pool: 73728 B
// pool overlays (lifetimes disjoint):
#define XST_OFF   (POOL)            // x stage fp32 [35][32]   (p0)
#define SC_OFF    (POOL)            // score slices [8][35][36] bf16 (p3)
#define MSG_OFF   (POOL)            // msg bf16 [256][64] swz  (p5-p6)
#define Q_OFF     (POOL + 32768)    // q bf16 [35][64]         (p2-p3)
#define K_OFF     (POOL + 37376)    // k bf16 [35][66]         (p2-p3)
#define AR_OFF    (POOL + 32768)    // A_r bf16 [48][64] swz   (p5)
#define XW_OFF    (POOL + 38912)    // xw  bf16 [64][64] swz   (p5)
#define H_OFF     (POOL + 32768)    // h bf16 [256][64] swz    (p5.75-p6)
#define AN_OFF    (POOL + 65536)    // An bf16 [3][35][35]     (p4-p5)
#define LDS_BYTES 163840

__device__ __forceinline__ unsigned short f2bf(float f) {
    unsigned int u = __float_as_uint(f);
    u += 0x7fffu + ((u >> 16) & 1u);
    return (unsigned short)(u >> 16);
}
__device__ __forceinline__ float bf2f(unsigned short s) {
    return __uint_as_float(((unsigned int)s) << 16);
}
__device__ __forceinline__ void divmod35(int g, int& r, int& n) {
    r = (g * 937) >> 15;   // exact for g < 245
    n = g - 35 * r;
}

__global__ void wrel_kernel(const float* __restrict__ coef, const float* __restrict__ V,
                            float* __restrict__ Wrel) {
    int idx = blockIdx.x * 256 + threadIdx.x;
    if (idx >= R_ * M_ * H_) return;
    int r = idx / (M_ * H_);
    int mh = idx - r * (M_ * H_);
    float acc = 0.f;
#pragma unroll
    for (int bb = 0; bb < 3; ++bb) acc += coef[r * 3 + bb] * V[bb * (M_ * H_) + mh];
    Wrel[idx] = acc;
}

__launch_bounds__(THREADS, 2)
__global__ void staa_kernel(
    const float* __restrict__ x, const float* __restrict__ As,
    const float* __restrict__ Af, const float* __restrict__ At,
    const float* __restrict__ h0, const float* __restrict__ Wq,
    const float* __restrict__ Wk, const float* __restrict__ Wrel,
    const float* __restrict__ Uz, const float* __restrict__ Wz, const float* __restrict__ bz,
    const float* __restrict__ Ur, const float* __restrict__ Wrg, const float* __restrict__ brg,
    const float* __restrict__ Uh, const float* __restrict__ Wh, const float* __restrict__ bh,
    float* __restrict__ out)
{
    extern __shared__ char smem[];
    const int b = blockIdx.x;
    const int tid = threadIdx.x;
    const int wv = tid >> 6;
    const int ln = tid & 63;

    // ---------------- init: pack weights into fragment-order bf16 ----------------
    {
        const float* Ws[6] = {Uz, Wz, Ur, Wrg, Uh, Wh};
#pragma unroll 1
        for (int mat = 0; mat < 6; ++mat) {
            const float* W = Ws[mat];
            for (int e = tid; e < 4096; e += THREADS) {
                int j = e >> 6, c = e & 63;
                int nt = c >> 4, ks = j >> 5, l = (((j >> 3) & 3) << 4) | (c & 15), i = j & 7;
                *(unsigned short*)(smem + W6_OFF + mat * 8192 + ((nt * 2 + ks) * 64 + l) * 16 + i * 2)
                    = f2bf(W[j * 64 + c]);
            }
        }
        for (int e = tid; e < 2 * 2048; e += THREADS) {
            int mat = e >> 11, rem = e & 2047;
            int j = rem >> 6, c = rem & 63;
            float v = (j < M_) ? (mat ? Wk : Wq)[j * 64 + c] : 0.f;
            int nt = c >> 4, l = (((j >> 3) & 3) << 4) | (c & 15), i = j & 7;
            *(unsigned short*)(smem + WQK_OFF + mat * 4096 + nt * 1024 + l * 16 + i * 2) = f2bf(v);
        }
        for (int e = tid; e < 7 * 2048; e += THREADS) {
            int r = e >> 11, rem = e & 2047;
            int j = rem >> 6, c = rem & 63;
            float v = (j < M_) ? Wrel[(r * M_ + j) * 64 + c] : 0.f;
            int nt = c >> 4, l = (((j >> 3) & 3) << 4) | (c & 15), i = j & 7;
            *(unsigned short*)(smem + WRELF_OFF + r * 4096 + nt * 1024 + l * 16 + i * 2) = f2bf(v);
        }
        if (tid < 64) {
            *(float*)(smem + BIAS_OFF + tid * 4) = bz[tid];
            *(float*)(smem + BIAS_OFF + 256 + tid * 4) = brg[tid];
            *(float*)(smem + BIAS_OFF + 512 + tid * 4) = bh[tid];
        }
    }
    __syncthreads();

    for (int t = 0; t < T_; ++t) {
        const float* __restrict__ hprev = (t == 0) ? h0 : (out + (size_t)(t - 1) * (R_ * B_ * N_ * H_));
        float* __restrict__ out_t = out + (size_t)t * (R_ * B_ * N_ * H_);
        const float* __restrict__ xt = x + ((size_t)t * B_ + b) * (N_ * M_);

        // ---- p0a: stage x (fp32, zero-padded to [35][32]) ----
        for (int e = tid; e < 35 * 32; e += THREADS) {
            int n = e >> 5, m = e & 31;
            *(float*)(smem + XST_OFF + e * 4) = (m < M_) ? xt[n * M_ + m] : 0.f;
        }
        __syncthreads();
        // ---- p0b: pack x into A-fragment order (rows pad to 48) ----
        for (int e = tid; e < 3 * 512; e += THREADS) {
            int mt = e >> 9, l = (e >> 3) & 63, i = e & 7;
            int row = mt * 16 + (l & 15);
            int k = ((l >> 4) << 3) + i;
            float v = (row < N_) ? *(const float*)(smem + XST_OFF + (row * 32 + k) * 4) : 0.f;
            *(unsigned short*)(smem + XFRAG_OFF + (mt * 64 + l) * 16 + i * 2) = f2bf(v);
        }
        __syncthreads();

        // ---- p2: q = x@Wq, k = x@Wk via MFMA ----
        for (int tile = wv; tile < 24; tile += 8) {
            int qk = (tile >= 12) ? 1 : 0;
            int tt = tile - 12 * qk;
            int mt = tt >> 2, nt = tt & 3;
            short8 a = *(const short8*)(smem + XFRAG_OFF + (mt * 64 + ln) * 16);
            short8 bb = *(const short8*)(smem + WQK_OFF + qk * 4096 + nt * 1024 + ln * 16);
            f32x4 d = {0.f, 0.f, 0.f, 0.f};
            d = __builtin_amdgcn_mfma_f32_16x16x32_bf16(a, bb, d, 0, 0, 0);
            int col = nt * 16 + (ln & 15);
#pragma unroll
            for (int j = 0; j < 4; ++j) {
                int row = mt * 16 + ((ln >> 4) << 2) + j;
                if (row < N_) {
                    if (qk) *(unsigned short*)(smem + K_OFF + (row * 66 + col) * 2) = f2bf(d[j]);
                    else    *(unsigned short*)(smem + Q_OFF + (row * 64 + col) * 2) = f2bf(d[j]);
                }
            }
        }
        __syncthreads();

        // ---- p3: scores + softmax; wave wv handles head wv ----
        {
            int m = ln;
            int mm = (m < N_) ? m : 0;
            float kreg[8];
#pragma unroll
            for (int d4 = 0; d4 < 4; ++d4) {
                unsigned int pr = *(const unsigned int*)(smem + K_OFF + mm * 132 + wv * 16 + d4 * 4);
                kreg[2 * d4]     = bf2f((unsigned short)(pr & 0xffffu));
                kreg[2 * d4 + 1] = bf2f((unsigned short)(pr >> 16));
            }
            for (int n = 0; n < N_; ++n) {
                short8 qv = *(const short8*)(smem + Q_OFF + n * 128 + wv * 16);
                float s = 0.f;
#pragma unroll
                for (int d = 0; d < 8; ++d) s += bf2f((unsigned short)qv[d]) * kreg[d];
                s *= 0.3535533905932738f;
                s = (m < N_) ? s : -1e30f;
                float mx = s;
#pragma unroll
                for (int off = 1; off < 64; off <<= 1) mx = fmaxf(mx, __shfl_xor(mx, off));
                float e = (m < N_) ? __expf(s - mx) : 0.f;
                float sum = e;
#pragma unroll
                for (int off = 1; off < 64; off <<= 1) sum += __shfl_xor(sum, off);
                float p = e / sum;
                if (m < N_)
                    *(unsigned short*)(smem + SC_OFF + (wv * 1260 + n * 36 + m) * 2) = f2bf(p);
            }
        }
        __syncthreads();

        // ---- p4: An = l2norm(A * S) (bf16 out) + pad-zero passes ----
        if (tid < 420) {
            int g = tid >> 2, sub = tid & 3;
            int mat = g / 35, j = g - 35 * mat;
            const float* __restrict__ A = (mat == 0) ? As : ((mat == 1) ? Af : At);
            float vals[9]; float ss = 0.f;
#pragma unroll
            for (int i = 0; i < 9; ++i) {
                int n = sub + 4 * i;
                float vv = 0.f;
                if (n < N_) {
                    float S = 0.f;
#pragma unroll
                    for (int hh2 = 0; hh2 < 8; ++hh2)
                        S += bf2f(*(const unsigned short*)(smem + SC_OFF + (hh2 * 1260 + n * 36 + j) * 2));
                    vv = A[n * N_ + j] * S;
                }
                vals[i] = vv; ss += vv * vv;
            }
            ss += __shfl_xor(ss, 1);
            ss += __shfl_xor(ss, 2);
            float inv = 1.f / fmaxf(sqrtf(ss), 1e-12f);
#pragma unroll
            for (int i = 0; i < 9; ++i) {
                int n = sub + 4 * i;
                if (n < N_)
                    *(unsigned short*)(smem + AN_OFF + (mat * 1225 + n * 35 + j) * 2) = f2bf(vals[i] * inv);
            }
        }
        // zero A_r pads (rows>=35 or k>=35), xw k-pads (k>=35), msg pad rows (245..255)
        for (int e = tid; e < 3072; e += THREADS) {
            int row = e >> 6, kk = e & 63;
            if (row >= N_ || kk >= N_) {
                int addr = AR_OFF + row * 128 + kk * 2; addr ^= (row & 7) << 4;
                *(unsigned short*)(smem + addr) = 0;
            }
        }
        for (int e = tid; e < 4096; e += THREADS) {
            int col = e >> 6, kk = e & 63;
            if (kk >= N_) {
                int addr = XW_OFF + col * 128 + kk * 2; addr ^= (col & 7) << 4;
                *(unsigned short*)(smem + addr) = 0;
            }
        }
        for (int e = tid; e < 176; e += THREADS) {
            short4v z4 = {0, 0, 0, 0};
            *(short4v*)(smem + MSG_OFF + 245 * 128 + e * 8) = z4;
        }
        __syncthreads();

        // ---- p5: relation loop: xw_r = x@Wrel_r ; A_r combo ; msg_r = A_r@xw_r ----
        for (int r = 0; r < R_; ++r) {
            float c0, c1, c2;
            switch (r) {
                case 0: c0 = 1.f;  c1 = 0.f;  c2 = 0.f;  break;
                case 1: c0 = 0.f;  c1 = 1.f;  c2 = 0.f;  break;
                case 2: c0 = 0.f;  c1 = 0.f;  c2 = 1.f;  break;
                case 3: c0 = .5f;  c1 = .5f;  c2 = 0.f;  break;
                case 4: c0 = .5f;  c1 = 0.f;  c2 = .5f;  break;
                case 5: c0 = 0.f;  c1 = .5f;  c2 = .5f;  break;
                default: c0 = c1 = c2 = (1.f / 3.f);     break;
            }
            // P1: xw MFMA + A_r combo
            for (int tile = wv; tile < 12; tile += 8) {
                int mt = tile >> 2, nt = tile & 3;
                short8 a = *(const short8*)(smem + XFRAG_OFF + (mt * 64 + ln) * 16);
                short8 bb = *(const short8*)(smem + WRELF_OFF + r * 4096 + nt * 1024 + ln * 16);
                f32x4 d = {0.f, 0.f, 0.f, 0.f};
                d = __builtin_amdgcn_mfma_f32_16x16x32_bf16(a, bb, d, 0, 0, 0);
                int col = nt * 16 + (ln & 15);
#pragma unroll
                for (int j = 0; j < 4; ++j) {
                    int krow = mt * 16 + ((ln >> 4) << 2) + j;
                    if (krow < N_) {
                        int addr = XW_OFF + col * 128 + krow * 2; addr ^= (col & 7) << 4;
                        *(unsigned short*)(smem + addr) = f2bf(d[j]);
                    }
                }
            }
            for (int e = tid; e < 1225; e += THREADS) {
                int n = e / 35, kk = e - 35 * (e / 35);
                float v = c0 * bf2f(*(const unsigned short*)(smem + AN_OFF + (n * 35 + kk) * 2))
                        + c1 * bf2f(*(const unsigned short*)(smem + AN_OFF + (1225 + n * 35 + kk) * 2))
                        + c2 * bf2f(*(const unsigned short*)(smem + AN_OFF + (2450 + n * 35 + kk) * 2));
                int addr = AR_OFF + n * 128 + kk * 2; addr ^= (n & 7) << 4;
                *(unsigned short*)(smem + addr) = f2bf(v);
            }
            __syncthreads();
            // P2: msg_r = relu(A_r @ xw_r)
            for (int tile = wv; tile < 12; tile += 8) {
                int mt = tile >> 2, nt = tile & 3;
                f32x4 d = {0.f, 0.f, 0.f, 0.f};
#pragma unroll
                for (int ks = 0; ks < 2; ++ks) {
                    int arow = mt * 16 + (ln & 15);
                    int aaddr = AR_OFF + arow * 128 + ks * 64 + ((ln >> 4) << 4); aaddr ^= (arow & 7) << 4;
                    short8 a = *(const short8*)(smem + aaddr);
                    int bcol = nt * 16 + (ln & 15);
                    int baddr = XW_OFF + bcol * 128 + ks * 64 + ((ln >> 4) << 4); baddr ^= (bcol & 7) << 4;
                    short8 bb = *(const short8*)(smem + baddr);
                    d = __builtin_amdgcn_mfma_f32_16x16x32_bf16(a, bb, d, 0, 0, 0);
                }
                int col = nt * 16 + (ln & 15);
#pragma unroll
                for (int j = 0; j < 4; ++j) {
                    int row = mt * 16 + ((ln >> 4) << 2) + j;
                    if (row < N_) {
                        int g = r * 35 + row;
                        int addr = MSG_OFF + g * 128 + col * 2; addr ^= (g & 7) << 4;
                        *(unsigned short*)(smem + addr) = f2bf(fmaxf(d[j], 0.f));
                    }
                }
            }
            __syncthreads();
        }

        // ---- p5.75: load h_prev -> bf16 LDS (A-layout, swz) ----
        for (int idx = tid; idx < 245 * 16; idx += THREADS) {
            int g = idx >> 4, c4 = (idx & 15) << 2;
            int rr, nn; divmod35(g, rr, nn);
            float4 hv = *(const float4*)(hprev + ((((rr << 8) + b) * 35 + nn) << 6) + c4);
            short4v s4 = { (short)f2bf(hv.x), (short)f2bf(hv.y), (short)f2bf(hv.z), (short)f2bf(hv.w) };
            int addr = H_OFF + g * 128 + c4 * 2; addr ^= (g & 7) << 4;
            *(short4v*)(smem + addr) = s4;
        }
        for (int e = tid; e < 176; e += THREADS) {
            short4v z4 = {0, 0, 0, 0};
            *(short4v*)(smem + H_OFF + 245 * 128 + e * 8) = z4;
        }
        __syncthreads();

        // ---- p6: gates (wave-private tiles; no barriers inside) ----
        {
            float bzv[4], brv[4], bhv[4];
#pragma unroll
            for (int nt = 0; nt < 4; ++nt) {
                int col = nt * 16 + (ln & 15);
                bzv[nt] = *(const float*)(smem + BIAS_OFF + col * 4);
                brv[nt] = *(const float*)(smem + BIAS_OFF + 256 + col * 4);
                bhv[nt] = *(const float*)(smem + BIAS_OFF + 512 + col * 4);
            }
#pragma unroll
            for (int mi = 0; mi < 2; ++mi) {
                const int mt = wv * 2 + mi;
                int offj[4], validj[4];
#pragma unroll
                for (int j = 0; j < 4; ++j) {
                    int row = mt * 16 + ((ln >> 4) << 2) + j;
                    int rr, nn; divmod35(row, rr, nn);
                    validj[j] = (row < 245);
                    offj[j] = ((((rr << 8) + b) * 35 + nn) << 6);
                }
                float hp[4][4];
#pragma unroll
                for (int nt = 0; nt < 4; ++nt) {
                    int col = nt * 16 + (ln & 15);
#pragma unroll
                    for (int j = 0; j < 4; ++j)
                        hp[nt][j] = validj[j] ? hprev[offj[j] + col] : 0.f;
                }
                short8 amsg[2], ah[2];
#pragma unroll
                for (int ks = 0; ks < 2; ++ks) {
                    int arow = mt * 16 + (ln & 15);
                    int maddr = MSG_OFF + arow * 128 + ks * 64 + ((ln >> 4) << 4); maddr ^= (arow & 7) << 4;
                    amsg[ks] = *(const short8*)(smem + maddr);
                    int haddr = H_OFF + arow * 128 + ks * 64 + ((ln >> 4) << 4); haddr ^= (arow & 7) << 4;
                    ah[ks] = *(const short8*)(smem + haddr);
                }
                f32x4 zacc[4], racc[4], macc[4];
#pragma unroll
                for (int nt = 0; nt < 4; ++nt) {
                    f32x4 z  = {bzv[nt], bzv[nt], bzv[nt], bzv[nt]};
                    f32x4 rg = {brv[nt], brv[nt], brv[nt], brv[nt]};
                    f32x4 mq = {bhv[nt], bhv[nt], bhv[nt], bhv[nt]};
#pragma unroll
                    for (int ks = 0; ks < 2; ++ks) {
                        const int fo = ((nt * 2 + ks) * 64 + ln) * 16;
                        short8 buz = *(const short8*)(smem + W6_OFF + 0 * 8192 + fo);
                        z  = __builtin_amdgcn_mfma_f32_16x16x32_bf16(amsg[ks], buz, z, 0, 0, 0);
                        short8 bwz = *(const short8*)(smem + W6_OFF + 1 * 8192 + fo);
                        z  = __builtin_amdgcn_mfma_f32_16x16x32_bf16(ah[ks],  bwz, z, 0, 0, 0);
                        short8 bur = *(const short8*)(smem + W6_OFF + 2 * 8192 + fo);
                        rg = __builtin_amdgcn_mfma_f32_16x16x32_bf16(amsg[ks], bur, rg, 0, 0, 0);
                        short8 bwr = *(const short8*)(smem + W6_OFF + 3 * 8192 + fo);
                        rg = __builtin_amdgcn_mfma_f32_16x16x32_bf16(ah[ks],  bwr, rg, 0, 0, 0);
                        short8 buh = *(const short8*)(smem + W6_OFF + 4 * 8192 + fo);
                        mq = __builtin_amdgcn_mfma_f32_16x16x32_bf16(amsg[ks], buh, mq, 0, 0, 0);
                    }
                    zacc[nt] = z; racc[nt] = rg; macc[nt] = mq;
                }
                // sigmoids; write rh over this wave's own msg rows
                f32x4 zv[4];
#pragma unroll
                for (int nt = 0; nt < 4; ++nt) {
                    int col = nt * 16 + (ln & 15);
#pragma unroll
                    for (int j = 0; j < 4; ++j) {
                        float zz = 1.f / (1.f + __expf(-zacc[nt][j]));
                        float rv = 1.f / (1.f + __expf(-racc[nt][j]));
                        zv[nt][j] = zz;
                        float rh = rv * hp[nt][j];
                        int row = mt * 16 + ((ln >> 4) << 2) + j;
                        int addr = MSG_OFF + row * 128 + col * 2; addr ^= (row & 7) << 4;
                        *(unsigned short*)(smem + addr) = f2bf(rh);
                    }
                }
                short8 arh[2];
#pragma unroll
                for (int ks = 0; ks < 2; ++ks) {
                    int arow = mt * 16 + (ln & 15);
                    int maddr = MSG_OFF + arow * 128 + ks * 64 + ((ln >> 4) << 4); maddr ^= (arow & 7) << 4;
                    arh[ks] = *(const short8*)(smem + maddr);
                }
#pragma unroll
                for (int nt = 0; nt < 4; ++nt) {
                    f32x4 mq = macc[nt];
#pragma unroll
                    for (int ks = 0; ks < 2; ++ks) {
                        const int fo = ((nt * 2 + ks) * 64 + ln) * 16;
                        short8 bwh = *(const short8*)(smem + W6_OFF + 5 * 8192 + fo);
                        mq = __builtin_amdgcn_mfma_f32_16x16x32_bf16(arh[ks], bwh, mq, 0, 0, 0);
                    }
                    int col = nt * 16 + (ln & 15);
#pragma unroll
                    for (int j = 0; j < 4; ++j) {
                        float e2 = __expf(2.f * mq[j]);
                        float hh2 = 1.f - 2.f / (1.f + e2);
                        float hpv = hp[nt][j];
                        float hn = hpv + zv[nt][j] * (hh2 - hpv);
                        if (validj[j]) out_t[offj[j] + col] = hn;
                    }
                }
            }
        }
        __syncthreads();  // end of t: pool regions recycled next iteration
    }
}

extern "C" void kernel_launch(void* const* d_in, const int* in_sizes, int n_in,
                              void* d_out, int out_size, void* d_ws, size_t ws_size,
                              hipStream_t stream) {
    const float* x    = (const float*)d_in[0];
    const float* As   = (const float*)d_in[1];
    const float* Af   = (const float*)d_in[2];
    const float* At   = (const float*)d_in[3];
    const float* h0   = (const float*)d_in[4];
    const float* Wq   = (const float*)d_in[5];
    const float* Wk   = (const float*)d_in[6];
    const float* V    = (const float*)d_in[7];
    const float* coef = (const float*)d_in[8];
    const float* Uz   = (const float*)d_in[9];
    const float* Wz   = (const float*)d_in[10];
    const float* bz   = (const float*)d_in[11];
    const float* Ur   = (const float*)d_in[12];
    const float* Wrg  = (const float*)d_in[13];
    const float* brg  = (const float*)d_in[14];
    const float* Uh   = (const float*)d_in[15];
    const float* Wh   = (const float*)d_in[16];
    const float* bh   = (const float*)d_in[17];
    float* out  = (float*)d_out;
    float* Wrel = (float*)d_ws;  // 7*29*64 fp32 = 51968 B

    hipFuncSetAttribute((const void*)staa_kernel,
                        hipFuncAttributeMaxDynamicSharedMemorySize, LDS_BYTES);

    hipLaunchKernelGGL(wrel_kernel, dim3((R_ * M_ * H_ + 255) / 256), dim3(256), 0, stream,
                       coef, V, Wrel);
    hipLaunchKernelGGL(staa_kernel, dim3(B_), dim3(THREADS), LDS_BYTES, stream,
                       x, As, Af, At, h0, Wq, Wk, Wrel,
                       Uz, Wz, bz, Ur, Wrg, brg, Uh, Wh, bh, out);
}